// Round 4
// baseline (254.008 us; speedup 1.0000x reference)
//
#include <hip/hip_runtime.h>
#include <hip/hip_bf16.h>

// LinearAttention (efficient attention): B=4 N=4096 D_MODEL=1024 H=16 DH=64
// Pipeline: cvt -> GEMM1(qkv, 256^2 counted-vmcnt 8-phase) -> ksoftmax stats
//           -> context(K^T V, +p2 fused) -> attn GEMM (q-softmax fused)
//           -> final GEMM (256^2, +bias, f32)

typedef unsigned short u16t;
typedef __bf16 bf16x8 __attribute__((ext_vector_type(8)));
typedef float f32x4 __attribute__((ext_vector_type(4)));
typedef unsigned short ushort8 __attribute__((ext_vector_type(8)));

__device__ __forceinline__ u16t f2bf(float f) {
    union { float f; unsigned int u; } v; v.f = f;
    unsigned int r = v.u + 0x7fffu + ((v.u >> 16) & 1u);
    return (u16t)(r >> 16);
}
__device__ __forceinline__ float bf2f(u16t h) {
    union { unsigned int u; float f; } v; v.u = ((unsigned int)h) << 16;
    return v.f;
}

#define GLOAD_LDS16(gptr, lptr) \
    __builtin_amdgcn_global_load_lds((const __attribute__((address_space(1))) unsigned int*)(gptr), \
                                     (__attribute__((address_space(3))) unsigned int*)(lptr), 16, 0, 0)

// ---------------- conversion kernels ----------------

__global__ void cvt_f32_bf16(const float* __restrict__ in, u16t* __restrict__ out, int n) {
    int i = (blockIdx.x * blockDim.x + threadIdx.x) * 4;
    int stride = gridDim.x * blockDim.x * 4;
    for (; i < n; i += stride) {
        float4 v = *(const float4*)(in + i);
        ushort4 o;
        o.x = f2bf(v.x); o.y = f2bf(v.y); o.z = f2bf(v.z); o.w = f2bf(v.w);
        *(ushort4*)(out + i) = o;
    }
}

// in [R][C] f32 -> out [C][R] bf16 (transpose + convert). grid (C/32, R/32), block (32,8)
__global__ void transpose_cvt(const float* __restrict__ in, u16t* __restrict__ out, int R, int C) {
    __shared__ float tile[32][33];
    int c0 = blockIdx.x * 32, r0 = blockIdx.y * 32;
    int tx = threadIdx.x, ty = threadIdx.y;
    for (int i = 0; i < 32; i += 8)
        tile[ty + i][tx] = in[(size_t)(r0 + ty + i) * C + c0 + tx];
    __syncthreads();
    for (int i = 0; i < 32; i += 8)
        out[(size_t)(c0 + ty + i) * R + r0 + tx] = f2bf(tile[tx][ty + i]);
}

// ---------------- 256x256 counted-vmcnt bf16 GEMM: C = A * Bt^T ----------------
// A [M][K] bf16 row-major, Bt [N][K] bf16 row-major (pre-transposed B).
// 512 threads = 8 waves (2 M x 4 N), per-wave output 128x64, BK=64, LDS 128KB dbuf.
//
// LDS per buffer (u16 units): A groups g=0..3 at g*4096 (group g = the 64 rows phase q=g
// reads: panel rows 32g..32g+31 of BOTH wave-row panels, i.e. global rows
// m0+32g+rr (+96 if rr>=32), rr=row-in-group). B at 16384: half h (128 rows) at h*8192.
// T2 swizzle: col-chunk stored XOR (row&7); staged via inverse-permuted global source
// (verified r3: SQ_LDS_BANK_CONFLICT == 0).
//
// Schedule (T3+T4): per phase q: 4 A ds_reads (+8 B reads at q0) | 2 stage calls (pair q
// for tile kt+1) | barrier | lgkmcnt(0) | 16 MFMA | counted vmcnt | barrier.
// Stage issue order per tile: {B-h0, B-h1, A-g0A-g1, A-g2A-g3} = consumption order of the
// NEXT tile. In-order vmcnt bookkeeping (steady state): end-of-phase waits {4,5,6,3};
// last tile (no stages): {2,1,0,-}. The barrier after each wait globalizes the per-wave
// vmcnt guarantee. Loads never drain to 0 in steady state.
template<int OUTF32, int BIAS>
__global__ __launch_bounds__(512, 2) void gemm256(const u16t* __restrict__ A, const u16t* __restrict__ Bt,
                                                  void* __restrict__ Cout, const float* __restrict__ bias,
                                                  int M, int N, int K, int NBX) {
    __shared__ __align__(16) u16t lds[65536];   // 128 KB
    const int t = threadIdx.x;
    const int l = t & 63, w = t >> 6;
    const int wm = w >> 2, wn = w & 3;

    // XCD-aware bijective swizzle (gridDim.x % 8 == 0)
    int cpx = gridDim.x >> 3;
    int wg = ((int)blockIdx.x & 7) * cpx + ((int)blockIdx.x >> 3);
    int bx = wg % NBX, by = wg / NBX;
    const int m0 = by * 256, n0 = bx * 256;
    const int NT = K >> 6;

    // fragment read addressing (u16 units, swizzle folded)
    const int colk0 = ((l >> 4) ^ (l & 7)) * 8;
    const int colk1 = colk0 ^ 32;
    const int abase = (wm * 32 + (l & 15)) * 64;                       // within A group
    const int bbase = 16384 + (wn >> 1) * 8192 + ((wn & 1) * 64 + (l & 15)) * 64;

    // staging addressing
    const int rr = w * 8 + (l >> 3);                                   // row within 64-row group
    const int coloff = ((l ^ (l >> 3)) & 7) * 8;                       // inverse swizzle on source
    const int rowA = rr + ((rr >= 32) ? 96 : 0);                       // A group-local -> global offset
    const u16t* pa_st = A  + (size_t)(m0 + rowA) * K + coloff;
    const u16t* pb_st = Bt + (size_t)(n0 + rr) * K + coloff;
    const int so = w * 512;

#define SPAIR(qq, kto, pb) do { \
    size_t k64_ = (size_t)(kto) * 64; \
    if ((qq) == 0) { \
        GLOAD_LDS16(pb_st + k64_,                  &lds[(pb) * 32768 + 16384 + so]); \
        GLOAD_LDS16(pb_st + k64_ + (size_t)64 * K, &lds[(pb) * 32768 + 20480 + so]); \
    } else if ((qq) == 1) { \
        GLOAD_LDS16(pb_st + k64_ + (size_t)128 * K, &lds[(pb) * 32768 + 24576 + so]); \
        GLOAD_LDS16(pb_st + k64_ + (size_t)192 * K, &lds[(pb) * 32768 + 28672 + so]); \
    } else if ((qq) == 2) { \
        GLOAD_LDS16(pa_st + k64_,                  &lds[(pb) * 32768 + so]); \
        GLOAD_LDS16(pa_st + k64_ + (size_t)32 * K, &lds[(pb) * 32768 + 4096 + so]); \
    } else { \
        GLOAD_LDS16(pa_st + k64_ + (size_t)64 * K, &lds[(pb) * 32768 + 8192 + so]); \
        GLOAD_LDS16(pa_st + k64_ + (size_t)96 * K, &lds[(pb) * 32768 + 12288 + so]); \
    } \
} while (0)

    f32x4 acc[8][4] = {};

    // prologue: stage tile 0 -> buf 0 in consumption order, counted wait
    SPAIR(0, 0, 0); SPAIR(1, 0, 0); SPAIR(2, 0, 0); SPAIR(3, 0, 0);
    asm volatile("s_waitcnt vmcnt(3)" ::: "memory");   // B + A-g0 landed
    __builtin_amdgcn_s_barrier();

    for (int kt = 0; kt < NT; ++kt) {
        const int p = kt & 1;
        const bool sn = (kt + 1 < NT);
        const u16t* lA = &lds[p * 32768];
        bf16x8 bfr[4][2];
#pragma unroll
        for (int q = 0; q < 4; ++q) {
            bf16x8 af[2][2];
            af[0][0] = *(const bf16x8*)&lA[q * 4096 + abase + colk0];
            af[0][1] = *(const bf16x8*)&lA[q * 4096 + abase + colk1];
            af[1][0] = *(const bf16x8*)&lA[q * 4096 + abase + 1024 + colk0];
            af[1][1] = *(const bf16x8*)&lA[q * 4096 + abase + 1024 + colk1];
            if (q == 0) {
#pragma unroll
                for (int ni = 0; ni < 4; ++ni) {
                    bfr[ni][0] = *(const bf16x8*)&lA[bbase + ni * 1024 + colk0];
                    bfr[ni][1] = *(const bf16x8*)&lA[bbase + ni * 1024 + colk1];
                }
            }
            if (sn) SPAIR(q, kt + 1, p ^ 1);
            __builtin_amdgcn_s_barrier();
            asm volatile("s_waitcnt lgkmcnt(0)" ::: "memory");
            __builtin_amdgcn_sched_barrier(0);
            __builtin_amdgcn_s_setprio(1);
#pragma unroll
            for (int dm = 0; dm < 2; ++dm)
#pragma unroll
                for (int ni = 0; ni < 4; ++ni)
#pragma unroll
                    for (int kk = 0; kk < 2; ++kk)
                        acc[q * 2 + dm][ni] = __builtin_amdgcn_mfma_f32_16x16x32_bf16(
                            af[dm][kk], bfr[ni][kk], acc[q * 2 + dm][ni], 0, 0, 0);
            __builtin_amdgcn_s_setprio(0);
            // counted end-of-phase wait: guarantees data read by phase q+1
            if (sn) {
                if (q == 0)      asm volatile("s_waitcnt vmcnt(4)" ::: "memory");
                else if (q == 1) asm volatile("s_waitcnt vmcnt(5)" ::: "memory");
                else if (q == 2) asm volatile("s_waitcnt vmcnt(6)" ::: "memory");
                else             asm volatile("s_waitcnt vmcnt(3)" ::: "memory");
            } else {
                if (q == 0)      asm volatile("s_waitcnt vmcnt(2)" ::: "memory");
                else if (q == 1) asm volatile("s_waitcnt vmcnt(1)" ::: "memory");
                else if (q == 2) asm volatile("s_waitcnt vmcnt(0)" ::: "memory");
            }
            __builtin_amdgcn_s_barrier();
        }
    }
#undef SPAIR

    // epilogue
#pragma unroll
    for (int mi = 0; mi < 8; ++mi) {
        int row = m0 + wm * 128 + mi * 16 + ((l >> 4) << 2);
#pragma unroll
        for (int ni = 0; ni < 4; ++ni) {
            int col = n0 + wn * 64 + ni * 16 + (l & 15);
            float bv = BIAS ? bias[col] : 0.f;
#pragma unroll
            for (int j = 0; j < 4; ++j) {
                float v = acc[mi][ni][j] + bv;
                if (OUTF32) ((float*)Cout)[(size_t)(row + j) * N + col] = v;
                else        ((u16t*)Cout)[(size_t)(row + j) * N + col] = f2bf(v);
            }
        }
    }
}

// ---------------- k softmax stats (over n=4096) ----------------
// pass1: grid (64 bh, 16 chunks of 256 n), block 256: partial max/sum per (bh,chunk,d)
__global__ void k_softmax_p1(const u16t* __restrict__ qkv, float* __restrict__ pmax, float* __restrict__ psum) {
    int bh = blockIdx.x, chunk = blockIdx.y;
    int b = bh >> 4, h = bh & 15;
    int d = threadIdx.x & 63, sub = threadIdx.x >> 6;
    size_t base = (size_t)b * 4096 * 3072 + 1024 + h * 64 + d;
    float m = -1e30f, s = 0.f;
    for (int i = 0; i < 64; i++) {
        int n = chunk * 256 + sub + i * 4;
        float v = bf2f(qkv[base + (size_t)n * 3072]);
        if (v > m) { s = s * expf(m - v) + 1.f; m = v; }
        else s += expf(v - m);
    }
    __shared__ float sm[4][64], ss[4][64];
    sm[sub][d] = m; ss[sub][d] = s;
    __syncthreads();
    if (threadIdx.x < 64) {
        float M = sm[0][d];
        for (int i = 1; i < 4; i++) M = fmaxf(M, sm[i][d]);
        float S = 0.f;
        for (int i = 0; i < 4; i++) S += ss[i][d] * expf(sm[i][d] - M);
        int o = (bh * 16 + chunk) * 64 + d;
        pmax[o] = M; psum[o] = S;
    }
}

// ---------------- context: ctxT[bh][e][d] = sum_n v[n][e] * ksoft[n][d] ----------------
// grid (64 bh, 8 chunks of 512 n), block 256. p2 (global stats combine) fused;
// k-softmax normalize fused into staging. 4 sub-chunks accumulated in reg -> 1 atomic pass.
__global__ __launch_bounds__(256) void context_kernel(const u16t* __restrict__ qkv,
                                                      const float* __restrict__ pmax, const float* __restrict__ psum,
                                                      float* __restrict__ ctxT) {
    int bh = blockIdx.x, chunk = blockIdx.y;
    int b = bh >> 4, h = bh & 15;
    __shared__ u16t kT[64][136];  // [d][n], pad to 136
    __shared__ u16t vT[64][136];  // [e][n]
    __shared__ float s_gm[64], s_gi[64];
    int t = threadIdx.x;
    if (t < 64) {
        float M = -1e30f;
        for (int c = 0; c < 16; c++) M = fmaxf(M, pmax[(bh * 16 + c) * 64 + t]);
        float S = 0.f;
        for (int c = 0; c < 16; c++) S += psum[(bh * 16 + c) * 64 + t] * expf(pmax[(bh * 16 + c) * 64 + t] - M);
        s_gm[t] = M; s_gi[t] = 1.f / S;
    }
    __syncthreads();
    int d = t & 63, g = t >> 6;
    float gm = s_gm[d], gi = s_gi[d];
    int lane = t & 63, w = t >> 6;
    f32x4 acc[4] = {};
    for (int sub = 0; sub < 4; sub++) {
        size_t rowbase = ((size_t)b * 4096 + chunk * 512 + sub * 128) * 3072;
        for (int i = 0; i < 32; i++) {
            int n = g + i * 4;
            size_t ro = rowbase + (size_t)n * 3072 + h * 64 + d;
            kT[d][n] = f2bf(expf(bf2f(qkv[ro + 1024]) - gm) * gi);
            vT[d][n] = qkv[ro + 2048];
        }
        __syncthreads();
#pragma unroll
        for (int ks = 0; ks < 4; ks++) {
            bf16x8 a = *(const bf16x8*)(&vT[w * 16 + (lane & 15)][ks * 32 + (lane >> 4) * 8]);
#pragma unroll
            for (int ct = 0; ct < 4; ct++) {
                bf16x8 bb = *(const bf16x8*)(&kT[ct * 16 + (lane & 15)][ks * 32 + (lane >> 4) * 8]);
                acc[ct] = __builtin_amdgcn_mfma_f32_16x16x32_bf16(a, bb, acc[ct], 0, 0, 0);
            }
        }
        __syncthreads();
    }
#pragma unroll
    for (int ct = 0; ct < 4; ct++) {
        int e = w * 16 + ((lane >> 4) << 2);
        int dd = ct * 16 + (lane & 15);
#pragma unroll
        for (int j = 0; j < 4; j++)
            atomicAdd(&ctxT[(size_t)bh * 4096 + (e + j) * 64 + dd], acc[ct][j]);
    }
}

// ---------------- attn GEMM (q-softmax fused): attn[n][h*64+e] = sum_d qsm[n][d] * ctxT[bh][e][d] ----
// grid (64 bh, 16 chunks of 256 n), block 256 (4 waves x 64 rows)
__global__ __launch_bounds__(256) void attn_gemm(const u16t* __restrict__ qkv, const float* __restrict__ ctxT,
                                                 u16t* __restrict__ attn) {
    int bh = blockIdx.x, chunk = blockIdx.y;
    int b = bh >> 4, h = bh & 15;
    __shared__ u16t q_lds[256][72];
    __shared__ u16t c_lds[64][72];
    int t = threadIdx.x;
#pragma unroll
    for (int i = 0; i < 16; i++) {
        int f = t + 256 * i;         // 0..4095
        int e = f >> 6, dd = f & 63;
        c_lds[e][dd] = f2bf(ctxT[(size_t)bh * 4096 + f]);
    }
    size_t qbase = ((size_t)b * 4096 + chunk * 256) * 3072 + h * 64;
#pragma unroll
    for (int i = 0; i < 8; i++) {
        int f = t + 256 * i;         // 0..2047 -> 256 rows x 8 quads
        int n = f >> 3, dg = f & 7;
        *(uint4*)(&q_lds[n][dg * 8]) = *(const uint4*)(&qkv[qbase + (size_t)n * 3072 + dg * 8]);
    }
    __syncthreads();
    // fused q softmax over d=64: one thread per row (256 threads = 256 rows)
    {
        ushort8 ch[8];
#pragma unroll
        for (int c = 0; c < 8; c++) ch[c] = *(const ushort8*)(&q_lds[t][c * 8]);
        float m = -1e30f;
#pragma unroll
        for (int c = 0; c < 8; c++)
#pragma unroll
            for (int j = 0; j < 8; j++) m = fmaxf(m, bf2f(ch[c][j]));
        float s = 0.f;
#pragma unroll
        for (int c = 0; c < 8; c++)
#pragma unroll
            for (int j = 0; j < 8; j++) s += expf(bf2f(ch[c][j]) - m);
        float inv = 0.125f / s;   // fold SCALE
#pragma unroll
        for (int c = 0; c < 8; c++) {
            ushort8 o;
#pragma unroll
            for (int j = 0; j < 8; j++) o[j] = f2bf(expf(bf2f(ch[c][j]) - m) * inv);
            *(ushort8*)(&q_lds[t][c * 8]) = o;
        }
    }
    __syncthreads();
    int lane = t & 63, w = t >> 6;
    f32x4 acc[4][4] = {};
#pragma unroll
    for (int ks = 0; ks < 2; ks++) {
        bf16x8 af[4], bfr[4];
#pragma unroll
        for (int mt = 0; mt < 4; mt++)
            af[mt] = *(const bf16x8*)(&q_lds[w * 64 + mt * 16 + (lane & 15)][ks * 32 + (lane >> 4) * 8]);
#pragma unroll
        for (int et = 0; et < 4; et++)
            bfr[et] = *(const bf16x8*)(&c_lds[et * 16 + (lane & 15)][ks * 32 + (lane >> 4) * 8]);
#pragma unroll
        for (int mt = 0; mt < 4; mt++)
#pragma unroll
            for (int et = 0; et < 4; et++)
                acc[mt][et] = __builtin_amdgcn_mfma_f32_16x16x32_bf16(af[mt], bfr[et], acc[mt][et], 0, 0, 0);
    }
    size_t abase = (size_t)b * 4096 + chunk * 256;
#pragma unroll
    for (int mt = 0; mt < 4; mt++) {
        int n = w * 64 + mt * 16 + ((lane >> 4) << 2);
#pragma unroll
        for (int et = 0; et < 4; et++) {
            int e = et * 16 + (lane & 15);
#pragma unroll
            for (int j = 0; j < 4; j++)
                attn[(abase + n + j) * 1024 + h * 64 + e] = f2bf(acc[mt][et][j]);
        }
    }
}

// ---------------- launch ----------------

extern "C" void kernel_launch(void* const* d_in, const int* in_sizes, int n_in,
                              void* d_out, int out_size, void* d_ws, size_t ws_size,
                              hipStream_t stream) {
    const float* x     = (const float*)d_in[0];
    const float* w_qkv = (const float*)d_in[1];
    const float* w_out = (const float*)d_in[2];
    const float* b_out = (const float*)d_in[3];
    float* out = (float*)d_out;
    char* ws = (char*)d_ws;

    // ws layout (bytes)
    size_t o_xb    = 0;                       // 16384*1024*2 = 33554432 (reused as attn)
    size_t o_wqkvT = 33554432;                // 3072*1024*2  = 6291456
    size_t o_woutT = 39845888;                // 1024*1024*2  = 2097152
    size_t o_qkv   = 41943040;                // 16384*3072*2 = 100663296
    size_t o_ctx   = 142606336;               // 64*64*64*4   = 1048576
    size_t o_pmax  = 143654912;               // 64*16*64*4   = 262144
    size_t o_psum  = 143917056;               // 262144
    size_t needed  = 144179200;
    if (ws_size < needed) return;             // visible failure if ws too small

    u16t* xb     = (u16t*)(ws + o_xb);
    u16t* attnb  = (u16t*)(ws + o_xb);        // reuse (xb dead after GEMM1)
    u16t* wqkvT  = (u16t*)(ws + o_wqkvT);
    u16t* woutT  = (u16t*)(ws + o_woutT);
    u16t* qkvb   = (u16t*)(ws + o_qkv);
    float* ctxT  = (float*)(ws + o_ctx);
    float* pmax  = (float*)(ws + o_pmax);
    float* psum  = (float*)(ws + o_psum);

    cvt_f32_bf16<<<2048, 256, 0, stream>>>(x, xb, 16777216);
    transpose_cvt<<<dim3(96, 32), dim3(32, 8), 0, stream>>>(w_qkv, wqkvT, 1024, 3072);
    transpose_cvt<<<dim3(32, 32), dim3(32, 8), 0, stream>>>(w_out, woutT, 1024, 1024);

    // GEMM1: [16384,1024] x [1024,3072] -> qkv ; grid 64*12 = 768 (div by 8)
    gemm256<0, 0><<<768, 512, 0, stream>>>(xb, wqkvT, qkvb, nullptr, 16384, 3072, 1024, 12);

    k_softmax_p1<<<dim3(64, 16), 256, 0, stream>>>(qkvb, pmax, psum);

    hipMemsetAsync(ctxT, 0, 64 * 64 * 64 * 4, stream);
    context_kernel<<<dim3(64, 8), 256, 0, stream>>>(qkvb, pmax, psum, ctxT);

    attn_gemm<<<dim3(64, 16), 256, 0, stream>>>(qkvb, ctxT, attnb);

    // GEMM2: [16384,1024] x [1024,1024] + bias -> out ; grid 64*4 = 256 (div by 8)
    gemm256<1, 1><<<256, 512, 0, stream>>>(attnb, woutT, out, b_out, 16384, 1024, 1024, 4);
}

// Round 5
// 253.524 us; speedup vs baseline: 1.0019x; 1.0019x over previous
//
#include <hip/hip_runtime.h>
#include <hip/hip_bf16.h>

// LinearAttention (efficient attention): B=4 N=4096 D_MODEL=1024 H=16 DH=64
// Pipeline: cvt -> GEMM1(qkv, 256^2 counted-vmcnt, unpinned sched) -> ksoftmax stats
//           -> context(K^T V, +p2 fused) -> attn GEMM (q-softmax fused)
//           -> final GEMM (256^2, +bias, f32)

typedef unsigned short u16t;
typedef __bf16 bf16x8 __attribute__((ext_vector_type(8)));
typedef float f32x4 __attribute__((ext_vector_type(4)));
typedef unsigned short ushort8 __attribute__((ext_vector_type(8)));

__device__ __forceinline__ u16t f2bf(float f) {
    union { float f; unsigned int u; } v; v.f = f;
    unsigned int r = v.u + 0x7fffu + ((v.u >> 16) & 1u);
    return (u16t)(r >> 16);
}
__device__ __forceinline__ float bf2f(u16t h) {
    union { unsigned int u; float f; } v; v.u = ((unsigned int)h) << 16;
    return v.f;
}

#define GLOAD_LDS16(gptr, lptr) \
    __builtin_amdgcn_global_load_lds((const __attribute__((address_space(1))) unsigned int*)(gptr), \
                                     (__attribute__((address_space(3))) unsigned int*)(lptr), 16, 0, 0)

// ---------------- conversion kernels ----------------

__global__ void cvt_f32_bf16(const float* __restrict__ in, u16t* __restrict__ out, int n) {
    int i = (blockIdx.x * blockDim.x + threadIdx.x) * 4;
    int stride = gridDim.x * blockDim.x * 4;
    for (; i < n; i += stride) {
        float4 v = *(const float4*)(in + i);
        ushort4 o;
        o.x = f2bf(v.x); o.y = f2bf(v.y); o.z = f2bf(v.z); o.w = f2bf(v.w);
        *(ushort4*)(out + i) = o;
    }
}

// in [R][C] f32 -> out [C][R] bf16 (transpose + convert). grid (C/32, R/32), block (32,8)
__global__ void transpose_cvt(const float* __restrict__ in, u16t* __restrict__ out, int R, int C) {
    __shared__ float tile[32][33];
    int c0 = blockIdx.x * 32, r0 = blockIdx.y * 32;
    int tx = threadIdx.x, ty = threadIdx.y;
    for (int i = 0; i < 32; i += 8)
        tile[ty + i][tx] = in[(size_t)(r0 + ty + i) * C + c0 + tx];
    __syncthreads();
    for (int i = 0; i < 32; i += 8)
        out[(size_t)(c0 + ty + i) * R + r0 + tx] = f2bf(tile[tx][ty + i]);
}

// ---------------- 256x256 counted-vmcnt bf16 GEMM: C = A * Bt^T ----------------
// A [M][K] bf16 row-major, Bt [N][K] bf16 row-major (pre-transposed B).
// 512 threads = 8 waves (2 M x 4 N), per-wave output 128x64, BK=64, LDS 128KB dbuf.
//
// LDS per buffer (u16 units): A groups g=0..3 at g*4096 (group g = the 64 rows phase q=g
// reads). B at 16384: half h (128 rows) at h*8192.
// T2 swizzle: col-chunk stored XOR (row&7); staged via inverse-permuted global source
// (verified r3: SQ_LDS_BANK_CONFLICT == 0).
//
// Schedule (T3+T4): per phase q: ds_reads | 2 stage calls | barrier | 16 MFMA
// (compiler-scheduled fine-grained lgkmcnt: ds_read latency drains UNDER MFMA issue —
// r4's explicit lgkmcnt(0)+sched_barrier(0) pin removed, m141 precedent) | counted
// vmcnt | barrier. Stage order per tile: {B-h0, B-h1, A-g01, A-g23}; end-of-phase
// waits (steady) {4,5,6,3}; last tile {2,1,0,-}. Loads never drain to 0 in steady state.
template<int OUTF32, int BIAS>
__global__ __launch_bounds__(512, 2) void gemm256(const u16t* __restrict__ A, const u16t* __restrict__ Bt,
                                                  void* __restrict__ Cout, const float* __restrict__ bias,
                                                  int M, int N, int K, int NBX) {
    __shared__ __align__(16) u16t lds[65536];   // 128 KB
    const int t = threadIdx.x;
    const int l = t & 63, w = t >> 6;
    const int wm = w >> 2, wn = w & 3;

    // XCD-aware bijective swizzle (gridDim.x % 8 == 0)
    int cpx = gridDim.x >> 3;
    int wg = ((int)blockIdx.x & 7) * cpx + ((int)blockIdx.x >> 3);
    int bx = wg % NBX, by = wg / NBX;
    const int m0 = by * 256, n0 = bx * 256;
    const int NT = K >> 6;

    // fragment read addressing (u16 units, swizzle folded)
    const int colk0 = ((l >> 4) ^ (l & 7)) * 8;
    const int colk1 = colk0 ^ 32;
    const int abase = (wm * 32 + (l & 15)) * 64;                       // within A group
    const int bbase = 16384 + (wn >> 1) * 8192 + ((wn & 1) * 64 + (l & 15)) * 64;

    // staging addressing
    const int rr = w * 8 + (l >> 3);                                   // row within 64-row group
    const int coloff = ((l ^ (l >> 3)) & 7) * 8;                       // inverse swizzle on source
    const int rowA = rr + ((rr >= 32) ? 96 : 0);                       // A group-local -> global offset
    const u16t* pa_st = A  + (size_t)(m0 + rowA) * K + coloff;
    const u16t* pb_st = Bt + (size_t)(n0 + rr) * K + coloff;
    const int so = w * 512;

#define SPAIR(qq, kto, pb) do { \
    size_t k64_ = (size_t)(kto) * 64; \
    if ((qq) == 0) { \
        GLOAD_LDS16(pb_st + k64_,                  &lds[(pb) * 32768 + 16384 + so]); \
        GLOAD_LDS16(pb_st + k64_ + (size_t)64 * K, &lds[(pb) * 32768 + 20480 + so]); \
    } else if ((qq) == 1) { \
        GLOAD_LDS16(pb_st + k64_ + (size_t)128 * K, &lds[(pb) * 32768 + 24576 + so]); \
        GLOAD_LDS16(pb_st + k64_ + (size_t)192 * K, &lds[(pb) * 32768 + 28672 + so]); \
    } else if ((qq) == 2) { \
        GLOAD_LDS16(pa_st + k64_,                  &lds[(pb) * 32768 + so]); \
        GLOAD_LDS16(pa_st + k64_ + (size_t)32 * K, &lds[(pb) * 32768 + 4096 + so]); \
    } else { \
        GLOAD_LDS16(pa_st + k64_ + (size_t)64 * K, &lds[(pb) * 32768 + 8192 + so]); \
        GLOAD_LDS16(pa_st + k64_ + (size_t)96 * K, &lds[(pb) * 32768 + 12288 + so]); \
    } \
} while (0)

    f32x4 acc[8][4] = {};

    // prologue: stage tile 0 -> buf 0 in consumption order, counted wait
    SPAIR(0, 0, 0); SPAIR(1, 0, 0); SPAIR(2, 0, 0); SPAIR(3, 0, 0);
    asm volatile("s_waitcnt vmcnt(3)" ::: "memory");   // B + A-g0 landed
    __builtin_amdgcn_s_barrier();

    for (int kt = 0; kt < NT; ++kt) {
        const int p = kt & 1;
        const bool sn = (kt + 1 < NT);
        const u16t* lA = &lds[p * 32768];
        bf16x8 bfr[4][2];
#pragma unroll
        for (int q = 0; q < 4; ++q) {
            bf16x8 af[2][2];
            af[0][0] = *(const bf16x8*)&lA[q * 4096 + abase + colk0];
            af[0][1] = *(const bf16x8*)&lA[q * 4096 + abase + colk1];
            af[1][0] = *(const bf16x8*)&lA[q * 4096 + abase + 1024 + colk0];
            af[1][1] = *(const bf16x8*)&lA[q * 4096 + abase + 1024 + colk1];
            if (q == 0) {
#pragma unroll
                for (int ni = 0; ni < 4; ++ni) {
                    bfr[ni][0] = *(const bf16x8*)&lA[bbase + ni * 1024 + colk0];
                    bfr[ni][1] = *(const bf16x8*)&lA[bbase + ni * 1024 + colk1];
                }
            }
            if (sn) SPAIR(q, kt + 1, p ^ 1);
            __builtin_amdgcn_s_barrier();
            __builtin_amdgcn_s_setprio(1);
#pragma unroll
            for (int dm = 0; dm < 2; ++dm)
#pragma unroll
                for (int ni = 0; ni < 4; ++ni)
#pragma unroll
                    for (int kk = 0; kk < 2; ++kk)
                        acc[q * 2 + dm][ni] = __builtin_amdgcn_mfma_f32_16x16x32_bf16(
                            af[dm][kk], bfr[ni][kk], acc[q * 2 + dm][ni], 0, 0, 0);
            __builtin_amdgcn_s_setprio(0);
            // counted end-of-phase wait: guarantees data read by phase q+1
            if (sn) {
                if (q == 0)      asm volatile("s_waitcnt vmcnt(4)" ::: "memory");
                else if (q == 1) asm volatile("s_waitcnt vmcnt(5)" ::: "memory");
                else if (q == 2) asm volatile("s_waitcnt vmcnt(6)" ::: "memory");
                else             asm volatile("s_waitcnt vmcnt(3)" ::: "memory");
            } else {
                if (q == 0)      asm volatile("s_waitcnt vmcnt(2)" ::: "memory");
                else if (q == 1) asm volatile("s_waitcnt vmcnt(1)" ::: "memory");
                else if (q == 2) asm volatile("s_waitcnt vmcnt(0)" ::: "memory");
            }
            __builtin_amdgcn_s_barrier();
        }
    }
#undef SPAIR

    // epilogue
#pragma unroll
    for (int mi = 0; mi < 8; ++mi) {
        int row = m0 + wm * 128 + mi * 16 + ((l >> 4) << 2);
#pragma unroll
        for (int ni = 0; ni < 4; ++ni) {
            int col = n0 + wn * 64 + ni * 16 + (l & 15);
            float bv = BIAS ? bias[col] : 0.f;
#pragma unroll
            for (int j = 0; j < 4; ++j) {
                float v = acc[mi][ni][j] + bv;
                if (OUTF32) ((float*)Cout)[(size_t)(row + j) * N + col] = v;
                else        ((u16t*)Cout)[(size_t)(row + j) * N + col] = f2bf(v);
            }
        }
    }
}

// ---------------- k softmax stats (over n=4096) ----------------
// pass1: grid (64 bh, 16 chunks of 256 n), block 256: partial max/sum per (bh,chunk,d)
__global__ void k_softmax_p1(const u16t* __restrict__ qkv, float* __restrict__ pmax, float* __restrict__ psum) {
    int bh = blockIdx.x, chunk = blockIdx.y;
    int b = bh >> 4, h = bh & 15;
    int d = threadIdx.x & 63, sub = threadIdx.x >> 6;
    size_t base = (size_t)b * 4096 * 3072 + 1024 + h * 64 + d;
    float m = -1e30f, s = 0.f;
    for (int i = 0; i < 64; i++) {
        int n = chunk * 256 + sub + i * 4;
        float v = bf2f(qkv[base + (size_t)n * 3072]);
        if (v > m) { s = s * expf(m - v) + 1.f; m = v; }
        else s += expf(v - m);
    }
    __shared__ float sm[4][64], ss[4][64];
    sm[sub][d] = m; ss[sub][d] = s;
    __syncthreads();
    if (threadIdx.x < 64) {
        float M = sm[0][d];
        for (int i = 1; i < 4; i++) M = fmaxf(M, sm[i][d]);
        float S = 0.f;
        for (int i = 0; i < 4; i++) S += ss[i][d] * expf(sm[i][d] - M);
        int o = (bh * 16 + chunk) * 64 + d;
        pmax[o] = M; psum[o] = S;
    }
}

// ---------------- context: ctxT[bh][e][d] = sum_n v[n][e] * ksoft[n][d] ----------------
// grid (64 bh, 8 chunks of 512 n), block 256. p2 (global stats combine) fused;
// k-softmax normalize fused into staging. 4 sub-chunks accumulated in reg -> 1 atomic pass.
__global__ __launch_bounds__(256) void context_kernel(const u16t* __restrict__ qkv,
                                                      const float* __restrict__ pmax, const float* __restrict__ psum,
                                                      float* __restrict__ ctxT) {
    int bh = blockIdx.x, chunk = blockIdx.y;
    int b = bh >> 4, h = bh & 15;
    __shared__ u16t kT[64][136];  // [d][n], pad to 136
    __shared__ u16t vT[64][136];  // [e][n]
    __shared__ float s_gm[64], s_gi[64];
    int t = threadIdx.x;
    if (t < 64) {
        float M = -1e30f;
        for (int c = 0; c < 16; c++) M = fmaxf(M, pmax[(bh * 16 + c) * 64 + t]);
        float S = 0.f;
        for (int c = 0; c < 16; c++) S += psum[(bh * 16 + c) * 64 + t] * expf(pmax[(bh * 16 + c) * 64 + t] - M);
        s_gm[t] = M; s_gi[t] = 1.f / S;
    }
    __syncthreads();
    int d = t & 63, g = t >> 6;
    float gm = s_gm[d], gi = s_gi[d];
    int lane = t & 63, w = t >> 6;
    f32x4 acc[4] = {};
    for (int sub = 0; sub < 4; sub++) {
        size_t rowbase = ((size_t)b * 4096 + chunk * 512 + sub * 128) * 3072;
        for (int i = 0; i < 32; i++) {
            int n = g + i * 4;
            size_t ro = rowbase + (size_t)n * 3072 + h * 64 + d;
            kT[d][n] = f2bf(expf(bf2f(qkv[ro + 1024]) - gm) * gi);
            vT[d][n] = qkv[ro + 2048];
        }
        __syncthreads();
#pragma unroll
        for (int ks = 0; ks < 4; ks++) {
            bf16x8 a = *(const bf16x8*)(&vT[w * 16 + (lane & 15)][ks * 32 + (lane >> 4) * 8]);
#pragma unroll
            for (int ct = 0; ct < 4; ct++) {
                bf16x8 bb = *(const bf16x8*)(&kT[ct * 16 + (lane & 15)][ks * 32 + (lane >> 4) * 8]);
                acc[ct] = __builtin_amdgcn_mfma_f32_16x16x32_bf16(a, bb, acc[ct], 0, 0, 0);
            }
        }
        __syncthreads();
    }
#pragma unroll
    for (int ct = 0; ct < 4; ct++) {
        int e = w * 16 + ((lane >> 4) << 2);
        int dd = ct * 16 + (lane & 15);
#pragma unroll
        for (int j = 0; j < 4; j++)
            atomicAdd(&ctxT[(size_t)bh * 4096 + (e + j) * 64 + dd], acc[ct][j]);
    }
}

// ---------------- attn GEMM (q-softmax fused): attn[n][h*64+e] = sum_d qsm[n][d] * ctxT[bh][e][d] ----
// grid (64 bh, 16 chunks of 256 n), block 256 (4 waves x 64 rows)
__global__ __launch_bounds__(256) void attn_gemm(const u16t* __restrict__ qkv, const float* __restrict__ ctxT,
                                                 u16t* __restrict__ attn) {
    int bh = blockIdx.x, chunk = blockIdx.y;
    int b = bh >> 4, h = bh & 15;
    __shared__ u16t q_lds[256][72];
    __shared__ u16t c_lds[64][72];
    int t = threadIdx.x;
#pragma unroll
    for (int i = 0; i < 16; i++) {
        int f = t + 256 * i;         // 0..4095
        int e = f >> 6, dd = f & 63;
        c_lds[e][dd] = f2bf(ctxT[(size_t)bh * 4096 + f]);
    }
    size_t qbase = ((size_t)b * 4096 + chunk * 256) * 3072 + h * 64;
#pragma unroll
    for (int i = 0; i < 8; i++) {
        int f = t + 256 * i;         // 0..2047 -> 256 rows x 8 quads
        int n = f >> 3, dg = f & 7;
        *(uint4*)(&q_lds[n][dg * 8]) = *(const uint4*)(&qkv[qbase + (size_t)n * 3072 + dg * 8]);
    }
    __syncthreads();
    // fused q softmax over d=64: one thread per row (256 threads = 256 rows)
    {
        ushort8 ch[8];
#pragma unroll
        for (int c = 0; c < 8; c++) ch[c] = *(const ushort8*)(&q_lds[t][c * 8]);
        float m = -1e30f;
#pragma unroll
        for (int c = 0; c < 8; c++)
#pragma unroll
            for (int j = 0; j < 8; j++) m = fmaxf(m, bf2f(ch[c][j]));
        float s = 0.f;
#pragma unroll
        for (int c = 0; c < 8; c++)
#pragma unroll
            for (int j = 0; j < 8; j++) s += expf(bf2f(ch[c][j]) - m);
        float inv = 0.125f / s;   // fold SCALE
#pragma unroll
        for (int c = 0; c < 8; c++) {
            ushort8 o;
#pragma unroll
            for (int j = 0; j < 8; j++) o[j] = f2bf(expf(bf2f(ch[c][j]) - m) * inv);
            *(ushort8*)(&q_lds[t][c * 8]) = o;
        }
    }
    __syncthreads();
    int lane = t & 63, w = t >> 6;
    f32x4 acc[4][4] = {};
#pragma unroll
    for (int ks = 0; ks < 2; ks++) {
        bf16x8 af[4], bfr[4];
#pragma unroll
        for (int mt = 0; mt < 4; mt++)
            af[mt] = *(const bf16x8*)(&q_lds[w * 64 + mt * 16 + (lane & 15)][ks * 32 + (lane >> 4) * 8]);
#pragma unroll
        for (int et = 0; et < 4; et++)
            bfr[et] = *(const bf16x8*)(&c_lds[et * 16 + (lane & 15)][ks * 32 + (lane >> 4) * 8]);
#pragma unroll
        for (int mt = 0; mt < 4; mt++)
#pragma unroll
            for (int et = 0; et < 4; et++)
                acc[mt][et] = __builtin_amdgcn_mfma_f32_16x16x32_bf16(af[mt], bfr[et], acc[mt][et], 0, 0, 0);
    }
    size_t abase = (size_t)b * 4096 + chunk * 256;
#pragma unroll
    for (int mt = 0; mt < 4; mt++) {
        int n = w * 64 + mt * 16 + ((lane >> 4) << 2);
#pragma unroll
        for (int et = 0; et < 4; et++) {
            int e = et * 16 + (lane & 15);
#pragma unroll
            for (int j = 0; j < 4; j++)
                attn[(abase + n + j) * 1024 + h * 64 + e] = f2bf(acc[mt][et][j]);
        }
    }
}

// ---------------- launch ----------------

extern "C" void kernel_launch(void* const* d_in, const int* in_sizes, int n_in,
                              void* d_out, int out_size, void* d_ws, size_t ws_size,
                              hipStream_t stream) {
    const float* x     = (const float*)d_in[0];
    const float* w_qkv = (const float*)d_in[1];
    const float* w_out = (const float*)d_in[2];
    const float* b_out = (const float*)d_in[3];
    float* out = (float*)d_out;
    char* ws = (char*)d_ws;

    // ws layout (bytes)
    size_t o_xb    = 0;                       // 16384*1024*2 = 33554432 (reused as attn)
    size_t o_wqkvT = 33554432;                // 3072*1024*2  = 6291456
    size_t o_woutT = 39845888;                // 1024*1024*2  = 2097152
    size_t o_qkv   = 41943040;                // 16384*3072*2 = 100663296
    size_t o_ctx   = 142606336;               // 64*64*64*4   = 1048576
    size_t o_pmax  = 143654912;               // 64*16*64*4   = 262144
    size_t o_psum  = 143917056;               // 262144
    size_t needed  = 144179200;
    if (ws_size < needed) return;             // visible failure if ws too small

    u16t* xb     = (u16t*)(ws + o_xb);
    u16t* attnb  = (u16t*)(ws + o_xb);        // reuse (xb dead after GEMM1)
    u16t* wqkvT  = (u16t*)(ws + o_wqkvT);
    u16t* woutT  = (u16t*)(ws + o_woutT);
    u16t* qkvb   = (u16t*)(ws + o_qkv);
    float* ctxT  = (float*)(ws + o_ctx);
    float* pmax  = (float*)(ws + o_pmax);
    float* psum  = (float*)(ws + o_psum);

    cvt_f32_bf16<<<2048, 256, 0, stream>>>(x, xb, 16777216);
    transpose_cvt<<<dim3(96, 32), dim3(32, 8), 0, stream>>>(w_qkv, wqkvT, 1024, 3072);
    transpose_cvt<<<dim3(32, 32), dim3(32, 8), 0, stream>>>(w_out, woutT, 1024, 1024);

    // GEMM1: [16384,1024] x [1024,3072] -> qkv ; grid 64*12 = 768 (div by 8)
    gemm256<0, 0><<<768, 512, 0, stream>>>(xb, wqkvT, qkvb, nullptr, 16384, 3072, 1024, 12);

    k_softmax_p1<<<dim3(64, 16), 256, 0, stream>>>(qkvb, pmax, psum);

    hipMemsetAsync(ctxT, 0, 64 * 64 * 64 * 4, stream);
    context_kernel<<<dim3(64, 8), 256, 0, stream>>>(qkvb, pmax, psum, ctxT);

    attn_gemm<<<dim3(64, 16), 256, 0, stream>>>(qkvb, ctxT, attnb);

    // GEMM2: [16384,1024] x [1024,1024] + bias -> out ; grid 64*4 = 256 (div by 8)
    gemm256<1, 1><<<256, 512, 0, stream>>>(attnb, woutT, out, b_out, 16384, 1024, 1024, 4);
}

// Round 6
// 229.072 us; speedup vs baseline: 1.1089x; 1.1067x over previous
//
#include <hip/hip_runtime.h>
#include <hip/hip_bf16.h>

// LinearAttention (efficient attention): B=4 N=4096 D_MODEL=1024 H=16 DH=64
// Pipeline: cvt -> GEMM1(qkv, 256^2 barrier-lite) -> ksoftmax stats
//           -> context(K^T V, +p2 fused) -> attn GEMM (q-softmax fused)
//           -> final GEMM (256^2, +bias, f32)

typedef unsigned short u16t;
typedef __bf16 bf16x8 __attribute__((ext_vector_type(8)));
typedef float f32x4 __attribute__((ext_vector_type(4)));
typedef unsigned short ushort8 __attribute__((ext_vector_type(8)));

__device__ __forceinline__ u16t f2bf(float f) {
    union { float f; unsigned int u; } v; v.f = f;
    unsigned int r = v.u + 0x7fffu + ((v.u >> 16) & 1u);
    return (u16t)(r >> 16);
}
__device__ __forceinline__ float bf2f(u16t h) {
    union { unsigned int u; float f; } v; v.u = ((unsigned int)h) << 16;
    return v.f;
}

#define GLOAD_LDS16(gptr, lptr) \
    __builtin_amdgcn_global_load_lds((const __attribute__((address_space(1))) unsigned int*)(gptr), \
                                     (__attribute__((address_space(3))) unsigned int*)(lptr), 16, 0, 0)
#define SFENCE asm volatile("" ::: "memory")

// ---------------- conversion kernels ----------------

__global__ void cvt_f32_bf16(const float* __restrict__ in, u16t* __restrict__ out, int n) {
    int i = (blockIdx.x * blockDim.x + threadIdx.x) * 4;
    int stride = gridDim.x * blockDim.x * 4;
    for (; i < n; i += stride) {
        float4 v = *(const float4*)(in + i);
        ushort4 o;
        o.x = f2bf(v.x); o.y = f2bf(v.y); o.z = f2bf(v.z); o.w = f2bf(v.w);
        *(ushort4*)(out + i) = o;
    }
}

// in [R][C] f32 -> out [C][R] bf16 (transpose + convert). grid (C/32, R/32), block (32,8)
__global__ void transpose_cvt(const float* __restrict__ in, u16t* __restrict__ out, int R, int C) {
    __shared__ float tile[32][33];
    int c0 = blockIdx.x * 32, r0 = blockIdx.y * 32;
    int tx = threadIdx.x, ty = threadIdx.y;
    for (int i = 0; i < 32; i += 8)
        tile[ty + i][tx] = in[(size_t)(r0 + ty + i) * C + c0 + tx];
    __syncthreads();
    for (int i = 0; i < 32; i += 8)
        out[(size_t)(c0 + ty + i) * R + r0 + tx] = f2bf(tile[tx][ty + i]);
}

// ---------------- 256x256 barrier-lite bf16 GEMM: C = A * Bt^T ----------------
// A [M][K] bf16 row-major, Bt [N][K] bf16 row-major (pre-transposed B).
// 512 threads = 8 waves (2 M x 4 N), per-wave output 128x64, BK=64, LDS 128KB dbuf.
//
// LDS per buffer (u16 units): A groups g=0..3 at g*4096 (group g rows = global
// m0+32g+rr, +96 if rr>=32). B at 16384: half h (128 rows) at h*8192.
// T2 swizzle: col-chunk stored XOR (row&7); staged via inverse-permuted global source
// (verified r3: SQ_LDS_BANK_CONFLICT == 0).
//
// Barrier-lite schedule (2 barriers / K-tile; r3-r5 lockstep diagnosis):
//   entry: vmcnt(2) [B-h0,B-h1,A-g01 landed] ; s_barrier
//   win1 : read B frags (8 b128) + A g0,g1 (8) ; issue S0,S1,S2 for kt+1 ; 32 MFMA
//   mid  : vmcnt(6) [A-g23 landed; 6 new in flight] (last tile: vmcnt(0)) ; s_barrier
//   win2 : read A g2,g3 (8) ; issue S3 ; 32 MFMA
// No lgkm pins: compiler drains ds_reads under MFMA issue; waves desync within
// windows so LDS and MFMA pipes overlap cross-wave. Waits precede barriers ->
// cross-wave staged data globalized. In-flight loads never below 2.
template<int OUTF32, int BIAS>
__global__ __launch_bounds__(512, 2) void gemm256(const u16t* __restrict__ A, const u16t* __restrict__ Bt,
                                                  void* __restrict__ Cout, const float* __restrict__ bias,
                                                  int M, int N, int K, int NBX) {
    __shared__ __align__(16) u16t lds[65536];   // 128 KB
    const int t = threadIdx.x;
    const int l = t & 63, w = t >> 6;
    const int wm = w >> 2, wn = w & 3;

    // XCD-aware bijective swizzle (gridDim.x % 8 == 0)
    int cpx = gridDim.x >> 3;
    int wg = ((int)blockIdx.x & 7) * cpx + ((int)blockIdx.x >> 3);
    int bx = wg % NBX, by = wg / NBX;
    const int m0 = by * 256, n0 = bx * 256;
    const int NT = K >> 6;

    // fragment read addressing (u16 units, swizzle folded)
    const int colk0 = ((l >> 4) ^ (l & 7)) * 8;
    const int colk1 = colk0 ^ 32;
    const int abase = (wm * 32 + (l & 15)) * 64;                       // within A group
    const int bbase = 16384 + (wn >> 1) * 8192 + ((wn & 1) * 64 + (l & 15)) * 64;

    // staging addressing
    const int rr = w * 8 + (l >> 3);                                   // row within 64-row group
    const int coloff = ((l ^ (l >> 3)) & 7) * 8;                       // inverse swizzle on source
    const int rowA = rr + ((rr >= 32) ? 96 : 0);                       // A group-local -> global offset
    const u16t* pa_st = A  + (size_t)(m0 + rowA) * K + coloff;
    const u16t* pb_st = Bt + (size_t)(n0 + rr) * K + coloff;
    const int so = w * 512;

#define SPAIR(qq, kto, pb) do { \
    size_t k64_ = (size_t)(kto) * 64; \
    if ((qq) == 0) { \
        GLOAD_LDS16(pb_st + k64_,                  &lds[(pb) * 32768 + 16384 + so]); \
        GLOAD_LDS16(pb_st + k64_ + (size_t)64 * K, &lds[(pb) * 32768 + 20480 + so]); \
    } else if ((qq) == 1) { \
        GLOAD_LDS16(pb_st + k64_ + (size_t)128 * K, &lds[(pb) * 32768 + 24576 + so]); \
        GLOAD_LDS16(pb_st + k64_ + (size_t)192 * K, &lds[(pb) * 32768 + 28672 + so]); \
    } else if ((qq) == 2) { \
        GLOAD_LDS16(pa_st + k64_,                  &lds[(pb) * 32768 + so]); \
        GLOAD_LDS16(pa_st + k64_ + (size_t)32 * K, &lds[(pb) * 32768 + 4096 + so]); \
    } else { \
        GLOAD_LDS16(pa_st + k64_ + (size_t)64 * K, &lds[(pb) * 32768 + 8192 + so]); \
        GLOAD_LDS16(pa_st + k64_ + (size_t)96 * K, &lds[(pb) * 32768 + 12288 + so]); \
    } \
} while (0)

    f32x4 acc[8][4] = {};

    // prologue: stage tile 0 -> buf 0. Fence keeps S3 youngest so counted waits
    // identify whole groups (compiler may permute gloads within a fence region).
    SPAIR(0, 0, 0); SPAIR(1, 0, 0); SPAIR(2, 0, 0);
    SFENCE;
    SPAIR(3, 0, 0);

    for (int kt = 0; kt < NT; ++kt) {
        const int p = kt & 1;
        const bool sn = (kt + 1 < NT);
        const u16t* lA = &lds[p * 32768];

        // ---- entry: B + A-g01 of this tile landed ----
        asm volatile("s_waitcnt vmcnt(2)" ::: "memory");
        __builtin_amdgcn_s_barrier();

        // ---- window 1: B frags + A groups 0,1 ; stage S0,S1,S2 ; 32 MFMA ----
        bf16x8 bfr[4][2];
#pragma unroll
        for (int ni = 0; ni < 4; ++ni) {
            bfr[ni][0] = *(const bf16x8*)&lA[bbase + ni * 1024 + colk0];
            bfr[ni][1] = *(const bf16x8*)&lA[bbase + ni * 1024 + colk1];
        }
        bf16x8 af1[2][2][2];  // [g][dm][kk], groups 0,1
#pragma unroll
        for (int g = 0; g < 2; ++g) {
            af1[g][0][0] = *(const bf16x8*)&lA[g * 4096 + abase + colk0];
            af1[g][0][1] = *(const bf16x8*)&lA[g * 4096 + abase + colk1];
            af1[g][1][0] = *(const bf16x8*)&lA[g * 4096 + abase + 1024 + colk0];
            af1[g][1][1] = *(const bf16x8*)&lA[g * 4096 + abase + 1024 + colk1];
        }
        if (sn) { SPAIR(0, kt + 1, p ^ 1); SPAIR(1, kt + 1, p ^ 1); SPAIR(2, kt + 1, p ^ 1); }
        __builtin_amdgcn_s_setprio(1);
#pragma unroll
        for (int g = 0; g < 2; ++g)
#pragma unroll
            for (int dm = 0; dm < 2; ++dm)
#pragma unroll
                for (int ni = 0; ni < 4; ++ni)
#pragma unroll
                    for (int kk = 0; kk < 2; ++kk)
                        acc[g * 2 + dm][ni] = __builtin_amdgcn_mfma_f32_16x16x32_bf16(
                            af1[g][dm][kk], bfr[ni][kk], acc[g * 2 + dm][ni], 0, 0, 0);
        __builtin_amdgcn_s_setprio(0);

        // ---- mid: A-g23 of this tile landed ----
        if (sn) asm volatile("s_waitcnt vmcnt(6)" ::: "memory");
        else    asm volatile("s_waitcnt vmcnt(0)" ::: "memory");
        __builtin_amdgcn_s_barrier();

        // ---- window 2: A groups 2,3 ; stage S3 ; 32 MFMA ----
        bf16x8 af2[2][2][2];  // groups 2,3
#pragma unroll
        for (int g = 0; g < 2; ++g) {
            af2[g][0][0] = *(const bf16x8*)&lA[(g + 2) * 4096 + abase + colk0];
            af2[g][0][1] = *(const bf16x8*)&lA[(g + 2) * 4096 + abase + colk1];
            af2[g][1][0] = *(const bf16x8*)&lA[(g + 2) * 4096 + abase + 1024 + colk0];
            af2[g][1][1] = *(const bf16x8*)&lA[(g + 2) * 4096 + abase + 1024 + colk1];
        }
        if (sn) SPAIR(3, kt + 1, p ^ 1);
        __builtin_amdgcn_s_setprio(1);
#pragma unroll
        for (int g = 0; g < 2; ++g)
#pragma unroll
            for (int dm = 0; dm < 2; ++dm)
#pragma unroll
                for (int ni = 0; ni < 4; ++ni)
#pragma unroll
                    for (int kk = 0; kk < 2; ++kk)
                        acc[4 + g * 2 + dm][ni] = __builtin_amdgcn_mfma_f32_16x16x32_bf16(
                            af2[g][dm][kk], bfr[ni][kk], acc[4 + g * 2 + dm][ni], 0, 0, 0);
        __builtin_amdgcn_s_setprio(0);
    }
#undef SPAIR

    // epilogue
#pragma unroll
    for (int mi = 0; mi < 8; ++mi) {
        int row = m0 + wm * 128 + mi * 16 + ((l >> 4) << 2);
#pragma unroll
        for (int ni = 0; ni < 4; ++ni) {
            int col = n0 + wn * 64 + ni * 16 + (l & 15);
            float bv = BIAS ? bias[col] : 0.f;
#pragma unroll
            for (int j = 0; j < 4; ++j) {
                float v = acc[mi][ni][j] + bv;
                if (OUTF32) ((float*)Cout)[(size_t)(row + j) * N + col] = v;
                else        ((u16t*)Cout)[(size_t)(row + j) * N + col] = f2bf(v);
            }
        }
    }
}

// ---------------- k softmax stats (over n=4096) ----------------
// pass1: grid (64 bh, 16 chunks of 256 n), block 256: partial max/sum per (bh,chunk,d)
// two-pass in registers (64 vals/thread), fast exp
__global__ void k_softmax_p1(const u16t* __restrict__ qkv, float* __restrict__ pmax, float* __restrict__ psum) {
    int bh = blockIdx.x, chunk = blockIdx.y;
    int b = bh >> 4, h = bh & 15;
    int d = threadIdx.x & 63, sub = threadIdx.x >> 6;
    size_t base = (size_t)b * 4096 * 3072 + 1024 + h * 64 + d + (size_t)(chunk * 256 + sub) * 3072;
    float v[64];
#pragma unroll
    for (int i = 0; i < 64; i++)
        v[i] = bf2f(qkv[base + (size_t)i * 4 * 3072]);
    float m = v[0];
#pragma unroll
    for (int i = 1; i < 64; i++) m = fmaxf(m, v[i]);
    float s = 0.f;
#pragma unroll
    for (int i = 0; i < 64; i++) s += __expf(v[i] - m);
    __shared__ float sm[4][64], ss[4][64];
    sm[sub][d] = m; ss[sub][d] = s;
    __syncthreads();
    if (threadIdx.x < 64) {
        float M = sm[0][d];
        for (int i = 1; i < 4; i++) M = fmaxf(M, sm[i][d]);
        float S = 0.f;
        for (int i = 0; i < 4; i++) S += ss[i][d] * __expf(sm[i][d] - M);
        int o = (bh * 16 + chunk) * 64 + d;
        pmax[o] = M; psum[o] = S;
    }
}

// ---------------- context: ctxT[bh][e][d] = sum_n v[n][e] * ksoft[n][d] ----------------
// grid (64 bh, 8 chunks of 512 n), block 256. p2 (global stats combine) fused;
// k-softmax normalize fused into staging. 4 sub-chunks accumulated in reg -> 1 atomic pass.
__global__ __launch_bounds__(256) void context_kernel(const u16t* __restrict__ qkv,
                                                      const float* __restrict__ pmax, const float* __restrict__ psum,
                                                      float* __restrict__ ctxT) {
    int bh = blockIdx.x, chunk = blockIdx.y;
    int b = bh >> 4, h = bh & 15;
    __shared__ u16t kT[64][136];  // [d][n], pad to 136
    __shared__ u16t vT[64][136];  // [e][n]
    __shared__ float s_gm[64], s_gi[64];
    int t = threadIdx.x;
    if (t < 64) {
        float M = -1e30f;
        for (int c = 0; c < 16; c++) M = fmaxf(M, pmax[(bh * 16 + c) * 64 + t]);
        float S = 0.f;
        for (int c = 0; c < 16; c++) S += psum[(bh * 16 + c) * 64 + t] * __expf(pmax[(bh * 16 + c) * 64 + t] - M);
        s_gm[t] = M; s_gi[t] = 1.f / S;
    }
    __syncthreads();
    int d = t & 63, g = t >> 6;
    float gm = s_gm[d], gi = s_gi[d];
    int lane = t & 63, w = t >> 6;
    f32x4 acc[4] = {};
    for (int sub = 0; sub < 4; sub++) {
        size_t rowbase = ((size_t)b * 4096 + chunk * 512 + sub * 128) * 3072;
        for (int i = 0; i < 32; i++) {
            int n = g + i * 4;
            size_t ro = rowbase + (size_t)n * 3072 + h * 64 + d;
            kT[d][n] = f2bf(__expf(bf2f(qkv[ro + 1024]) - gm) * gi);
            vT[d][n] = qkv[ro + 2048];
        }
        __syncthreads();
#pragma unroll
        for (int ks = 0; ks < 4; ks++) {
            bf16x8 a = *(const bf16x8*)(&vT[w * 16 + (lane & 15)][ks * 32 + (lane >> 4) * 8]);
#pragma unroll
            for (int ct = 0; ct < 4; ct++) {
                bf16x8 bb = *(const bf16x8*)(&kT[ct * 16 + (lane & 15)][ks * 32 + (lane >> 4) * 8]);
                acc[ct] = __builtin_amdgcn_mfma_f32_16x16x32_bf16(a, bb, acc[ct], 0, 0, 0);
            }
        }
        __syncthreads();
    }
#pragma unroll
    for (int ct = 0; ct < 4; ct++) {
        int e = w * 16 + ((lane >> 4) << 2);
        int dd = ct * 16 + (lane & 15);
#pragma unroll
        for (int j = 0; j < 4; j++)
            atomicAdd(&ctxT[(size_t)bh * 4096 + (e + j) * 64 + dd], acc[ct][j]);
    }
}

// ---------------- attn GEMM (q-softmax fused): attn[n][h*64+e] = sum_d qsm[n][d] * ctxT[bh][e][d] ----
// grid (64 bh, 16 chunks of 256 n), block 256 (4 waves x 64 rows)
__global__ __launch_bounds__(256) void attn_gemm(const u16t* __restrict__ qkv, const float* __restrict__ ctxT,
                                                 u16t* __restrict__ attn) {
    int bh = blockIdx.x, chunk = blockIdx.y;
    int b = bh >> 4, h = bh & 15;
    __shared__ u16t q_lds[256][72];
    __shared__ u16t c_lds[64][72];
    int t = threadIdx.x;
#pragma unroll
    for (int i = 0; i < 16; i++) {
        int f = t + 256 * i;         // 0..4095
        int e = f >> 6, dd = f & 63;
        c_lds[e][dd] = f2bf(ctxT[(size_t)bh * 4096 + f]);
    }
    size_t qbase = ((size_t)b * 4096 + chunk * 256) * 3072 + h * 64;
#pragma unroll
    for (int i = 0; i < 8; i++) {
        int f = t + 256 * i;         // 0..2047 -> 256 rows x 8 quads
        int n = f >> 3, dg = f & 7;
        *(uint4*)(&q_lds[n][dg * 8]) = *(const uint4*)(&qkv[qbase + (size_t)n * 3072 + dg * 8]);
    }
    __syncthreads();
    // fused q softmax over d=64: one thread per row (256 threads = 256 rows)
    {
        ushort8 ch[8];
#pragma unroll
        for (int c = 0; c < 8; c++) ch[c] = *(const ushort8*)(&q_lds[t][c * 8]);
        float m = -1e30f;
#pragma unroll
        for (int c = 0; c < 8; c++)
#pragma unroll
            for (int j = 0; j < 8; j++) m = fmaxf(m, bf2f(ch[c][j]));
        float s = 0.f;
#pragma unroll
        for (int c = 0; c < 8; c++)
#pragma unroll
            for (int j = 0; j < 8; j++) s += __expf(bf2f(ch[c][j]) - m);
        float inv = 0.125f / s;   // fold SCALE
#pragma unroll
        for (int c = 0; c < 8; c++) {
            ushort8 o;
#pragma unroll
            for (int j = 0; j < 8; j++) o[j] = f2bf(__expf(bf2f(ch[c][j]) - m) * inv);
            *(ushort8*)(&q_lds[t][c * 8]) = o;
        }
    }
    __syncthreads();
    int lane = t & 63, w = t >> 6;
    f32x4 acc[4][4] = {};
#pragma unroll
    for (int ks = 0; ks < 2; ks++) {
        bf16x8 af[4], bfr[4];
#pragma unroll
        for (int mt = 0; mt < 4; mt++)
            af[mt] = *(const bf16x8*)(&q_lds[w * 64 + mt * 16 + (lane & 15)][ks * 32 + (lane >> 4) * 8]);
#pragma unroll
        for (int et = 0; et < 4; et++)
            bfr[et] = *(const bf16x8*)(&c_lds[et * 16 + (lane & 15)][ks * 32 + (lane >> 4) * 8]);
#pragma unroll
        for (int mt = 0; mt < 4; mt++)
#pragma unroll
            for (int et = 0; et < 4; et++)
                acc[mt][et] = __builtin_amdgcn_mfma_f32_16x16x32_bf16(af[mt], bfr[et], acc[mt][et], 0, 0, 0);
    }
    size_t abase = (size_t)b * 4096 + chunk * 256;
#pragma unroll
    for (int mt = 0; mt < 4; mt++) {
        int n = w * 64 + mt * 16 + ((lane >> 4) << 2);
#pragma unroll
        for (int et = 0; et < 4; et++) {
            int e = et * 16 + (lane & 15);
#pragma unroll
            for (int j = 0; j < 4; j++)
                attn[(abase + n + j) * 1024 + h * 64 + e] = f2bf(acc[mt][et][j]);
        }
    }
}

// ---------------- launch ----------------

extern "C" void kernel_launch(void* const* d_in, const int* in_sizes, int n_in,
                              void* d_out, int out_size, void* d_ws, size_t ws_size,
                              hipStream_t stream) {
    const float* x     = (const float*)d_in[0];
    const float* w_qkv = (const float*)d_in[1];
    const float* w_out = (const float*)d_in[2];
    const float* b_out = (const float*)d_in[3];
    float* out = (float*)d_out;
    char* ws = (char*)d_ws;

    // ws layout (bytes)
    size_t o_xb    = 0;                       // 16384*1024*2 = 33554432 (reused as attn)
    size_t o_wqkvT = 33554432;                // 3072*1024*2  = 6291456
    size_t o_woutT = 39845888;                // 1024*1024*2  = 2097152
    size_t o_qkv   = 41943040;                // 16384*3072*2 = 100663296
    size_t o_ctx   = 142606336;               // 64*64*64*4   = 1048576
    size_t o_pmax  = 143654912;               // 64*16*64*4   = 262144
    size_t o_psum  = 143917056;               // 262144
    size_t needed  = 144179200;
    if (ws_size < needed) return;             // visible failure if ws too small

    u16t* xb     = (u16t*)(ws + o_xb);
    u16t* attnb  = (u16t*)(ws + o_xb);        // reuse (xb dead after GEMM1)
    u16t* wqkvT  = (u16t*)(ws + o_wqkvT);
    u16t* woutT  = (u16t*)(ws + o_woutT);
    u16t* qkvb   = (u16t*)(ws + o_qkv);
    float* ctxT  = (float*)(ws + o_ctx);
    float* pmax  = (float*)(ws + o_pmax);
    float* psum  = (float*)(ws + o_psum);

    cvt_f32_bf16<<<2048, 256, 0, stream>>>(x, xb, 16777216);
    transpose_cvt<<<dim3(96, 32), dim3(32, 8), 0, stream>>>(w_qkv, wqkvT, 1024, 3072);
    transpose_cvt<<<dim3(32, 32), dim3(32, 8), 0, stream>>>(w_out, woutT, 1024, 1024);

    // GEMM1: [16384,1024] x [1024,3072] -> qkv ; grid 64*12 = 768 (div by 8)
    gemm256<0, 0><<<768, 512, 0, stream>>>(xb, wqkvT, qkvb, nullptr, 16384, 3072, 1024, 12);

    k_softmax_p1<<<dim3(64, 16), 256, 0, stream>>>(qkvb, pmax, psum);

    hipMemsetAsync(ctxT, 0, 64 * 64 * 64 * 4, stream);
    context_kernel<<<dim3(64, 8), 256, 0, stream>>>(qkvb, pmax, psum, ctxT);

    attn_gemm<<<dim3(64, 16), 256, 0, stream>>>(qkvb, ctxT, attnb);

    // GEMM2: [16384,1024] x [1024,1024] + bias -> out ; grid 64*4 = 256 (div by 8)
    gemm256<1, 1><<<256, 512, 0, stream>>>(attnb, woutT, out, b_out, 16384, 1024, 1024, 4);
}